// Round 1
// baseline (175.858 us; speedup 1.0000x reference)
//
#include <hip/hip_runtime.h>
#include <hip/hip_bf16.h>

#define B 128
#define N 1024
#define L 512
#define D 64

typedef float f32x4 __attribute__((ext_vector_type(4)));
typedef short bf16x8 __attribute__((ext_vector_type(8)));

// 8 fp32 -> 8 bf16 (RNE) via packed HW cvt
__device__ inline bf16x8 cvt8(float4 f0, float4 f1) {
    union { __hip_bfloat162 h2[4]; bf16x8 v; } u;
    u.h2[0] = __float22bfloat162_rn(make_float2(f0.x, f0.y));
    u.h2[1] = __float22bfloat162_rn(make_float2(f0.z, f0.w));
    u.h2[2] = __float22bfloat162_rn(make_float2(f1.x, f1.y));
    u.h2[3] = __float22bfloat162_rn(make_float2(f1.z, f1.w));
    return u.v;
}

// Named members (not an array) so depth-2 prefetch stays in registers (no
// runtime-indexed ext_vector arrays -> scratch).
struct PF { float4 a, b, c, d; };

// Pre-pass: ntok[b] / nreg[b] so sim blocks don't each re-read 6KB of masks
// and pay a serial reduce+barrier prologue. counts[0..B) = ntok, [B..2B) = nreg.
__global__ __launch_bounds__(256) void count_kernel(
        const float* __restrict__ tmask, const float* __restrict__ imask,
        int* __restrict__ counts) {
    int b = blockIdx.x, tid = threadIdx.x;
    int w = tid >> 6, lane = tid & 63;
    float ts = 0.f, is = 0.f;
    const float* tm = tmask + (size_t)b * N;
#pragma unroll
    for (int i = 0; i < N / 256; ++i) ts += tm[tid + i * 256];
    const float* im = imask + (size_t)b * L;
#pragma unroll
    for (int i = 0; i < L / 256; ++i) is += im[tid + i * 256];
    for (int off = 32; off; off >>= 1) {
        ts += __shfl_down(ts, off);
        is += __shfl_down(is, off);
    }
    __shared__ float red[8];
    if (lane == 0) { red[w] = ts; red[4 + w] = is; }
    __syncthreads();
    if (tid == 0) counts[b]     = (int)(red[0] + red[1] + red[2] + red[3] + 0.5f);
    if (tid == 1) counts[B + b] = (int)(red[4] + red[5] + red[6] + red[7] + 0.5f);
}

// grid = 1536 blocks (s,b,token-chunk) x 256 thr.
// Latency-oriented rework vs previous version:
//  - counts precomputed (no mask pass; early-exit blocks exit after 1 load)
//  - staging loads CLAMP region index to nreg-1: duplicates of valid rows are
//    max-neutral, so every chunk is a full 64-region chunk -> tile loop is
//    compile-time unrolled (8 ds_read_b128 hoisted, LDS latency hidden)
//  - depth-2 register prefetch (pfA/pfB) over the double-buffered LDS: vmcnt
//    wait at store(k+1) has ~2 compute phases of slack vs ~900cyc HBM latency
__global__ __launch_bounds__(256, 4) void sim_kernel(
        const float* __restrict__ T, const float* __restrict__ I,
        const int* __restrict__ counts,
        const int* __restrict__ Iimp, const int* __restrict__ Simp,
        float* __restrict__ partials) {
    int blk = blockIdx.x;          // 0..1535
    int chunk = blk & 3;
    int bs = blk >> 2;
    int b = bs & (B - 1);
    int s = bs >> 7;
    int Tb = b, Ib = b;
    if (s == 1) Tb = Simp[b];
    else if (s == 2) Ib = Iimp[b];

    int tid = threadIdx.x;
    int w = tid >> 6;
    int lane = tid & 63;
    int q = lane >> 4;
    int c = lane & 15;

    int ntok = counts[Tb];         // uniform -> s_load
    int nreg = counts[B + Ib];

    int tok0 = chunk << 8;
    // ntok >= N/4 = 256 by construction: chunk 0 never exits (skips the wait)
    if (chunk != 0) {
        if (tok0 >= ntok) {
            if (tid == 0) partials[blk] = 0.f;
            return;
        }
    }

    __shared__ unsigned short ldsI[2][64 * D];   // 2 x 8 KB bf16, fragment order
    __shared__ float red[4];

    // ---- A fragments: 4 token tiles x 2 K-halves (rows >= ntok masked at sum) ----
    int wt0 = tok0 + w * 64;
    bf16x8 afrag[4][2];
#pragma unroll
    for (int tt = 0; tt < 4; ++tt) {
        const float* trow = T + ((size_t)Tb * N + wt0 + tt * 16 + c) * D;
#pragma unroll
        for (int h = 0; h < 2; ++h) {
            const float4* p = (const float4*)(trow + h * 32 + q * 8);
            afrag[tt][h] = cvt8(p[0], p[1]);
        }
    }

    float mx[4][4];
#pragma unroll
    for (int tt = 0; tt < 4; ++tt)
#pragma unroll
        for (int i = 0; i < 4; ++i) mx[tt][i] = -3.0e38f;

    // ---- staging thread map: two 16B bf16 chunks per thread ----
    //   16B chunk ci = g*64+ln (g=rt*2+h): region rt*16+(ln&15), d = h*32+(ln>>4)*8
    int r_loc[2], db_loc[2];
#pragma unroll
    for (int j = 0; j < 2; ++j) {
        int ci = tid + j * 256;
        int g = ci >> 6, ln = ci & 63;
        r_loc[j] = (g >> 1) * 16 + (ln & 15);
        db_loc[j] = (g & 1) * 32 + (ln >> 4) * 8;
    }
    const float* Ibase = I + (size_t)Ib * L * D;

    PF pfA, pfB;

    // clamped issue (region duplicates beyond nreg are max-neutral)
    auto issueK = [&](int k, PF& pf) {
        int rbase = k << 6;
        int r0 = rbase + r_loc[0]; if (r0 >= nreg) r0 = nreg - 1;
        int r1 = rbase + r_loc[1]; if (r1 >= nreg) r1 = nreg - 1;
        const float4* p0 = (const float4*)(Ibase + (size_t)r0 * D + db_loc[0]);
        pf.a = p0[0]; pf.b = p0[1];
        const float4* p1 = (const float4*)(Ibase + (size_t)r1 * D + db_loc[1]);
        pf.c = p1[0]; pf.d = p1[1];
    };
    auto storeK = [&](int k, const PF& pf) {
        char* dst = (char*)&ldsI[k & 1][0] + (size_t)tid * 16;
        *(bf16x8*)dst = cvt8(pf.a, pf.b);
        *(bf16x8*)(dst + 4096) = cvt8(pf.c, pf.d);
    };

    // chunks 0 and 1 are always fully valid (nreg >= 128): unclamped issue,
    // no dependence on the nreg load
    {
        const float4* p0 = (const float4*)(Ibase + (size_t)r_loc[0] * D + db_loc[0]);
        pfA.a = p0[0]; pfA.b = p0[1];
        const float4* p1 = (const float4*)(Ibase + (size_t)r_loc[1] * D + db_loc[1]);
        pfA.c = p1[0]; pfA.d = p1[1];
        const float4* p2 = (const float4*)(Ibase + (size_t)(64 + r_loc[0]) * D + db_loc[0]);
        pfB.a = p2[0]; pfB.b = p2[1];
        const float4* p3 = (const float4*)(Ibase + (size_t)(64 + r_loc[1]) * D + db_loc[1]);
        pfB.c = p3[0]; pfB.d = p3[1];
    }
    storeK(0, pfA);
    __syncthreads();

    int nchunks = (nreg + 63) >> 6;              // always >= 2
    for (int k = 0; k < nchunks; ++k) {
        if (k + 2 < nchunks) {                   // refill the set consumed by store(k)
            if (k & 1) issueK(k + 2, pfB);
            else       issueK(k + 2, pfA);
        }

        // full 64-region chunk, compile-time unrolled: 8 ds_read_b128 + 32 MFMA
        const char* base = (const char*)&ldsI[k & 1][0] + (size_t)lane * 16;
#pragma unroll
        for (int rt = 0; rt < 4; ++rt) {
            bf16x8 b0 = *(const bf16x8*)(base + (rt * 2 + 0) * 1024);
            bf16x8 b1 = *(const bf16x8*)(base + (rt * 2 + 1) * 1024);
#pragma unroll
            for (int tt = 0; tt < 4; ++tt) {
                f32x4 acc = {0.f, 0.f, 0.f, 0.f};
                acc = __builtin_amdgcn_mfma_f32_16x16x32_bf16(afrag[tt][0], b0, acc, 0, 0, 0);
                acc = __builtin_amdgcn_mfma_f32_16x16x32_bf16(afrag[tt][1], b1, acc, 0, 0, 0);
#pragma unroll
                for (int i = 0; i < 4; ++i) mx[tt][i] = fmaxf(mx[tt][i], acc[i]);
            }
        }

        if (k + 1 < nchunks) {
            if (k & 1) storeK(k + 1, pfA);       // set (k+1)&1, issued at iter k-1
            else       storeK(k + 1, pfB);
            __syncthreads();                     // one barrier per iteration
        }
    }

    // ---- cross-lane max over 16 region-cols ----
#pragma unroll
    for (int m = 1; m < 16; m <<= 1) {
#pragma unroll
        for (int tt = 0; tt < 4; ++tt)
#pragma unroll
            for (int i = 0; i < 4; ++i)
                mx[tt][i] = fmaxf(mx[tt][i], __shfl_xor(mx[tt][i], m));
    }

    // ---- masked token sum (C layout: row = q*4 + i) ----
    float bsum = 0.f;
    if (c == 0) {
#pragma unroll
        for (int tt = 0; tt < 4; ++tt)
#pragma unroll
            for (int i = 0; i < 4; ++i) {
                int row = wt0 + tt * 16 + q * 4 + i;
                if (row < ntok) bsum += mx[tt][i];
            }
    }
    for (int off = 32; off; off >>= 1) bsum += __shfl_down(bsum, off);
    if (lane == 0) red[w] = bsum;
    __syncthreads();
    if (tid == 0)
        partials[blk] = (red[0] + red[1] + red[2] + red[3]) / (float)ntok;
}

// 1 block x 384 threads: fold 1536 partials -> 384 sims -> hinge -> loss
__global__ void loss_kernel(const float* __restrict__ partials,
                            float* __restrict__ out) {
    int tid = threadIdx.x;  // 0..383
    __shared__ float simsL[384];
    __shared__ float w6[6];
    const float4* p4 = (const float4*)partials;
    float4 v = p4[tid];
    simsL[tid] = v.x + v.y + v.z + v.w;
    __syncthreads();
    float per = 0.f;
    if (tid < B) {
        float anc  = simsL[tid];
        float simp = simsL[B + tid];
        float iimp = simsL[2 * B + tid];
        per = fmaxf(1.f + iimp - anc, 0.f) + fmaxf(1.f + simp - anc, 0.f);
    }
    for (int off = 32; off; off >>= 1) per += __shfl_down(per, off);
    if ((tid & 63) == 0) w6[tid >> 6] = per;
    __syncthreads();
    if (tid == 0)
        out[0] = (w6[0] + w6[1] + w6[2] + w6[3] + w6[4] + w6[5]) / (float)B;
}

extern "C" void kernel_launch(void* const* d_in, const int* in_sizes, int n_in,
                              void* d_out, int out_size, void* d_ws, size_t ws_size,
                              hipStream_t stream) {
    const float* T     = (const float*)d_in[0];
    const float* I     = (const float*)d_in[1];
    const float* tmask = (const float*)d_in[2];
    const float* imask = (const float*)d_in[3];
    const int*   Iimp  = (const int*)d_in[4];
    const int*   Simp  = (const int*)d_in[5];
    int*   counts   = (int*)d_ws;                 // 256 ints
    float* partials = (float*)d_ws + 256;         // 1536 floats

    count_kernel<<<B, 256, 0, stream>>>(tmask, imask, counts);
    sim_kernel<<<3 * B * 4, 256, 0, stream>>>(T, I, counts, Iimp, Simp, partials);
    loss_kernel<<<1, 384, 0, stream>>>(partials, (float*)d_out);
}

// Round 2
// 156.632 us; speedup vs baseline: 1.1228x; 1.1228x over previous
//
#include <hip/hip_runtime.h>
#include <hip/hip_bf16.h>

#define B 128
#define N 1024
#define L 512
#define D 64

typedef float f32x4 __attribute__((ext_vector_type(4)));
typedef short bf16x8 __attribute__((ext_vector_type(8)));

// 8 fp32 -> 8 bf16 (RNE) via packed HW cvt
__device__ inline bf16x8 cvt8(float4 f0, float4 f1) {
    union { __hip_bfloat162 h2[4]; bf16x8 v; } u;
    u.h2[0] = __float22bfloat162_rn(make_float2(f0.x, f0.y));
    u.h2[1] = __float22bfloat162_rn(make_float2(f0.z, f0.w));
    u.h2[2] = __float22bfloat162_rn(make_float2(f1.x, f1.y));
    u.h2[3] = __float22bfloat162_rn(make_float2(f1.z, f1.w));
    return u.v;
}

// Pre-pass: ntok[b] / nreg[b] so sim blocks don't each re-read 6KB of masks
// and pay a serial reduce+barrier prologue. counts[0..B) = ntok, [B..2B) = nreg.
__global__ __launch_bounds__(256) void count_kernel(
        const float* __restrict__ tmask, const float* __restrict__ imask,
        int* __restrict__ counts) {
    int b = blockIdx.x, tid = threadIdx.x;
    int w = tid >> 6, lane = tid & 63;
    float ts = 0.f, is = 0.f;
    const float* tm = tmask + (size_t)b * N;
#pragma unroll
    for (int i = 0; i < N / 256; ++i) ts += tm[tid + i * 256];
    const float* im = imask + (size_t)b * L;
#pragma unroll
    for (int i = 0; i < L / 256; ++i) is += im[tid + i * 256];
    for (int off = 32; off; off >>= 1) {
        ts += __shfl_down(ts, off);
        is += __shfl_down(is, off);
    }
    __shared__ float red[8];
    if (lane == 0) { red[w] = ts; red[4 + w] = is; }
    __syncthreads();
    if (tid == 0) counts[b]     = (int)(red[0] + red[1] + red[2] + red[3] + 0.5f);
    if (tid == 1) counts[B + b] = (int)(red[4] + red[5] + red[6] + red[7] + 0.5f);
}

// grid = 1536 blocks (s,b,token-chunk) x 256 thr.
// vs the 51us round-0 kernel:
//  - counts precomputed (no per-block mask pass / serial prologue)
//  - staging loads CLAMP region index to nreg-1: duplicates of valid rows are
//    max-neutral, so every chunk is a full 64-region chunk -> inner tile loop
//    is compile-time unrolled (8 ds_read_b128 hoisted+interleaved, immediate
//    offsets) instead of a runtime-bounded loop with serial LDS exposure.
// Pipeline stays the PROVEN depth-1 (round-1's depth-2 via lambda-ref structs
// went to scratch: 108MB WRITE_SIZE). pf[4] is only ever statically indexed.
__global__ __launch_bounds__(256, 4) void sim_kernel(
        const float* __restrict__ T, const float* __restrict__ I,
        const int* __restrict__ counts,
        const int* __restrict__ Iimp, const int* __restrict__ Simp,
        float* __restrict__ partials) {
    int blk = blockIdx.x;          // 0..1535
    int chunk = blk & 3;
    int bs = blk >> 2;
    int b = bs & (B - 1);
    int s = bs >> 7;
    int Tb = b, Ib = b;
    if (s == 1) Tb = Simp[b];
    else if (s == 2) Ib = Iimp[b];

    int tid = threadIdx.x;
    int w = tid >> 6;
    int lane = tid & 63;
    int q = lane >> 4;
    int c = lane & 15;

    int ntok = counts[Tb];         // block-uniform
    int nreg = counts[B + Ib];

    int tok0 = chunk << 8;
    // ntok >= N/4 = 256 by construction: chunk 0 never exits
    if (chunk != 0 && tok0 >= ntok) {
        if (tid == 0) partials[blk] = 0.f;
        return;
    }

    __shared__ unsigned short ldsI[2][64 * D];   // 2 x 8 KB bf16, fragment order
    __shared__ float red[4];

    // ---- A fragments: 4 token tiles x 2 K-halves (rows >= ntok masked at sum) ----
    int wt0 = tok0 + w * 64;
    bf16x8 afrag[4][2];
#pragma unroll
    for (int tt = 0; tt < 4; ++tt) {
        const float* trow = T + ((size_t)Tb * N + wt0 + tt * 16 + c) * D;
#pragma unroll
        for (int h = 0; h < 2; ++h) {
            const float4* p = (const float4*)(trow + h * 32 + q * 8);
            afrag[tt][h] = cvt8(p[0], p[1]);
        }
    }

    float mx[4][4];
#pragma unroll
    for (int tt = 0; tt < 4; ++tt)
#pragma unroll
        for (int i = 0; i < 4; ++i) mx[tt][i] = -3.0e38f;

    // ---- staging thread map: two 16B bf16 chunks per thread ----
    //   16B chunk ci = g*64+ln (g=rt*2+h): region rt*16+(ln&15), d = h*32+(ln>>4)*8
    int r_loc[2], db_loc[2];
#pragma unroll
    for (int j = 0; j < 2; ++j) {
        int ci = tid + j * 256;
        int g = ci >> 6, ln = ci & 63;
        r_loc[j] = (g >> 1) * 16 + (ln & 15);
        db_loc[j] = (g & 1) * 32 + (ln >> 4) * 8;
    }
    const float* Ibase = I + (size_t)Ib * L * D;
    int nchunks = (nreg + 63) >> 6;              // always >= 2 (nreg >= 128)
    float4 pf[4];                                // static indexing only

    auto issue = [&](int k) {
        int rbase = k << 6;
#pragma unroll
        for (int j = 0; j < 2; ++j) {
            int r = rbase + r_loc[j];
            if (r >= nreg) r = nreg - 1;         // duplicate valid row: max-neutral
            const float4* p = (const float4*)(Ibase + (size_t)r * D + db_loc[j]);
            pf[2 * j] = p[0];
            pf[2 * j + 1] = p[1];
        }
    };
    auto store = [&](int k) {
#pragma unroll
        for (int j = 0; j < 2; ++j) {
            int ci = tid + j * 256;
            *(bf16x8*)((char*)&ldsI[k & 1][0] + (size_t)ci * 16) = cvt8(pf[2 * j], pf[2 * j + 1]);
        }
    };

    issue(0);
    store(0);
    __syncthreads();

    for (int k = 0; k < nchunks; ++k) {
        if (k + 1 < nchunks) issue(k + 1);       // loads in flight over compute

        // full 64-region chunk, compile-time unrolled: 8 ds_read_b128 + 32 MFMA
        const char* base = (const char*)&ldsI[k & 1][0] + (size_t)lane * 16;
#pragma unroll
        for (int rt = 0; rt < 4; ++rt) {
            bf16x8 b0 = *(const bf16x8*)(base + (rt * 2 + 0) * 1024);
            bf16x8 b1 = *(const bf16x8*)(base + (rt * 2 + 1) * 1024);
#pragma unroll
            for (int tt = 0; tt < 4; ++tt) {
                f32x4 acc = {0.f, 0.f, 0.f, 0.f};
                acc = __builtin_amdgcn_mfma_f32_16x16x32_bf16(afrag[tt][0], b0, acc, 0, 0, 0);
                acc = __builtin_amdgcn_mfma_f32_16x16x32_bf16(afrag[tt][1], b1, acc, 0, 0, 0);
#pragma unroll
                for (int i = 0; i < 4; ++i) mx[tt][i] = fmaxf(mx[tt][i], acc[i]);
            }
        }

        if (k + 1 < nchunks) {
            store(k + 1);                        // vmcnt wait here, post-compute
            __syncthreads();                     // one barrier per iteration
        }
    }

    // ---- cross-lane max over 16 region-cols ----
#pragma unroll
    for (int m = 1; m < 16; m <<= 1) {
#pragma unroll
        for (int tt = 0; tt < 4; ++tt)
#pragma unroll
            for (int i = 0; i < 4; ++i)
                mx[tt][i] = fmaxf(mx[tt][i], __shfl_xor(mx[tt][i], m));
    }

    // ---- masked token sum (C layout: row = q*4 + i) ----
    float bsum = 0.f;
    if (c == 0) {
#pragma unroll
        for (int tt = 0; tt < 4; ++tt)
#pragma unroll
            for (int i = 0; i < 4; ++i) {
                int row = wt0 + tt * 16 + q * 4 + i;
                if (row < ntok) bsum += mx[tt][i];
            }
    }
    for (int off = 32; off; off >>= 1) bsum += __shfl_down(bsum, off);
    if (lane == 0) red[w] = bsum;
    __syncthreads();
    if (tid == 0)
        partials[blk] = (red[0] + red[1] + red[2] + red[3]) / (float)ntok;
}

// 1 block x 384 threads: fold 1536 partials -> 384 sims -> hinge -> loss
__global__ void loss_kernel(const float* __restrict__ partials,
                            float* __restrict__ out) {
    int tid = threadIdx.x;  // 0..383
    __shared__ float simsL[384];
    __shared__ float w6[6];
    const float4* p4 = (const float4*)partials;
    float4 v = p4[tid];
    simsL[tid] = v.x + v.y + v.z + v.w;
    __syncthreads();
    float per = 0.f;
    if (tid < B) {
        float anc  = simsL[tid];
        float simp = simsL[B + tid];
        float iimp = simsL[2 * B + tid];
        per = fmaxf(1.f + iimp - anc, 0.f) + fmaxf(1.f + simp - anc, 0.f);
    }
    for (int off = 32; off; off >>= 1) per += __shfl_down(per, off);
    if ((tid & 63) == 0) w6[tid >> 6] = per;
    __syncthreads();
    if (tid == 0)
        out[0] = (w6[0] + w6[1] + w6[2] + w6[3] + w6[4] + w6[5]) / (float)B;
}

extern "C" void kernel_launch(void* const* d_in, const int* in_sizes, int n_in,
                              void* d_out, int out_size, void* d_ws, size_t ws_size,
                              hipStream_t stream) {
    const float* T     = (const float*)d_in[0];
    const float* I     = (const float*)d_in[1];
    const float* tmask = (const float*)d_in[2];
    const float* imask = (const float*)d_in[3];
    const int*   Iimp  = (const int*)d_in[4];
    const int*   Simp  = (const int*)d_in[5];
    int*   counts   = (int*)d_ws;                 // 256 ints
    float* partials = (float*)d_ws + 256;         // 1536 floats

    count_kernel<<<B, 256, 0, stream>>>(tmask, imask, counts);
    sim_kernel<<<3 * B * 4, 256, 0, stream>>>(T, I, counts, Iimp, Simp, partials);
    loss_kernel<<<1, 384, 0, stream>>>(partials, (float*)d_out);
}

// Round 3
// 129.878 us; speedup vs baseline: 1.3540x; 1.2060x over previous
//
#include <hip/hip_runtime.h>
#include <hip/hip_bf16.h>

#define B 128
#define N 1024
#define L 512
#define D 64

typedef float f32x4 __attribute__((ext_vector_type(4)));
typedef short bf16x8 __attribute__((ext_vector_type(8)));

// 8 fp32 -> 8 bf16 (RNE) via packed HW cvt
__device__ inline bf16x8 cvt8(float4 f0, float4 f1) {
    union { __hip_bfloat162 h2[4]; bf16x8 v; } u;
    u.h2[0] = __float22bfloat162_rn(make_float2(f0.x, f0.y));
    u.h2[1] = __float22bfloat162_rn(make_float2(f0.z, f0.w));
    u.h2[2] = __float22bfloat162_rn(make_float2(f1.x, f1.y));
    u.h2[3] = __float22bfloat162_rn(make_float2(f1.z, f1.w));
    return u.v;
}

// async global->LDS DMA, 16B per lane; LDS dest must be linear base+lane*16
__device__ __forceinline__ void gload16(const void* g, void* l) {
    __builtin_amdgcn_global_load_lds(
        (const __attribute__((address_space(1))) void*)g,
        (__attribute__((address_space(3))) void*)l, 16, 0, 0);
}

// Pre-pass: ntok[b] / nreg[b]. counts[0..B) = ntok, [B..2B) = nreg.
__global__ __launch_bounds__(256) void count_kernel(
        const float* __restrict__ tmask, const float* __restrict__ imask,
        int* __restrict__ counts) {
    int b = blockIdx.x, tid = threadIdx.x;
    int w = tid >> 6, lane = tid & 63;
    float ts = 0.f, is = 0.f;
    const float* tm = tmask + (size_t)b * N;
#pragma unroll
    for (int i = 0; i < N / 256; ++i) ts += tm[tid + i * 256];
    const float* im = imask + (size_t)b * L;
#pragma unroll
    for (int i = 0; i < L / 256; ++i) is += im[tid + i * 256];
    for (int off = 32; off; off >>= 1) {
        ts += __shfl_down(ts, off);
        is += __shfl_down(is, off);
    }
    __shared__ float red[8];
    if (lane == 0) { red[w] = ts; red[4 + w] = is; }
    __syncthreads();
    if (tid == 0) counts[b]     = (int)(red[0] + red[1] + red[2] + red[3] + 0.5f);
    if (tid == 1) counts[B + b] = (int)(red[4] + red[5] + red[6] + red[7] + 0.5f);
}

// grid = 1536 blocks (s,b,token-chunk) x 256 thr.
// Staging rework vs round-2 (which spilled pf[] -> 65MB scratch writes):
//  - ZERO staging registers: global_load_lds DMAs fp32 I-chunks straight to
//    LDS in fragment order; bf16 cvt happens at read (VALU pipe, overlaps MFMA)
//  - 3-buffer depth-2 pipeline with counted vmcnt (T3/T4-lite): per-iter wait
//    is vmcnt(4) = "stage(k+1) done, stage(k+2) still in flight" -> HBM
//    latency gets ~2 compute phases of cover; never vmcnt(0) in steady state
//  - hazard ledger: buf[(k+2)%3] last read iter k-1, protected by that iter's
//    lgkmcnt(0)+s_barrier; prologue vmcnt(0) isolates stage ops in the counter
// LDS fp32 fragment layout, 16B chunk ci in [0,1024):
//   fh=ci>>7 (=rt*2+h), half=(ci>>6)&1, ln=ci&63:
//   region (fh>>1)*16+(ln&15), floats (fh&1)*32+(ln>>4)*8+half*4 .. +4
// read for (rt,h): f0 = lds[fh*2048 + lane*16], f1 = +1024 -> cvt8 -> bf16x8
__global__ __launch_bounds__(256, 3) void sim_kernel(
        const float* __restrict__ T, const float* __restrict__ I,
        const int* __restrict__ counts,
        const int* __restrict__ Iimp, const int* __restrict__ Simp,
        float* __restrict__ partials) {
    int blk = blockIdx.x;          // 0..1535
    int chunk = blk & 3;
    int bs = blk >> 2;
    int b = bs & (B - 1);
    int s = bs >> 7;
    int Tb = b, Ib = b;
    if (s == 1) Tb = Simp[b];
    else if (s == 2) Ib = Iimp[b];

    int tid = threadIdx.x;
    int w = tid >> 6;
    int lane = tid & 63;
    int q = lane >> 4;
    int c = lane & 15;

    int ntok = counts[Tb];         // block-uniform
    int nreg = counts[B + Ib];

    int tok0 = chunk << 8;
    // ntok >= N/4 = 256 by construction: chunk 0 never exits
    if (chunk != 0 && tok0 >= ntok) {
        if (tid == 0) partials[blk] = 0.f;
        return;
    }

    __shared__ float ldsI[3][4096];              // 3 x 16 KB fp32 chunk buffers
    __shared__ float red[4];

    // ---- A fragments: 4 token tiles x 2 K-halves (rows >= ntok masked at sum) ----
    int wt0 = tok0 + w * 64;
    bf16x8 afrag[4][2];
#pragma unroll
    for (int tt = 0; tt < 4; ++tt) {
        const float* trow = T + ((size_t)Tb * N + wt0 + tt * 16 + c) * D;
#pragma unroll
        for (int h = 0; h < 2; ++h) {
            const float4* p = (const float4*)(trow + h * 32 + q * 8);
            afrag[tt][h] = cvt8(p[0], p[1]);
        }
    }

    float mx[4][4];
#pragma unroll
    for (int tt = 0; tt < 4; ++tt)
#pragma unroll
        for (int i = 0; i < 4; ++i) mx[tt][i] = -3.0e38f;

    // ---- staging decode: 4 x 16B DMA per thread per chunk ----
    int rloc[4], foff[4];
#pragma unroll
    for (int j = 0; j < 4; ++j) {
        int ci = tid + j * 256;
        int fh = ci >> 7, idx = ci & 127, half = idx >> 6, ln2 = idx & 63;
        rloc[j] = (fh >> 1) * 16 + (ln2 & 15);
        foff[j] = (fh & 1) * 32 + (ln2 >> 4) * 8 + half * 4;
    }
    const float* Ibase = I + (size_t)Ib * L * D;
    int nchunks = (nreg + 63) >> 6;              // always >= 2 (nreg >= 128)
    int nregm1 = nreg - 1;

    auto stage = [&](int k) {
        float* buf = &ldsI[k % 3][0];
        int rbase = k << 6;
#pragma unroll
        for (int j = 0; j < 4; ++j) {
            int r = rbase + rloc[j];
            if (r > nregm1) r = nregm1;          // duplicate valid row: max-neutral
            gload16(Ibase + (size_t)r * D + foff[j], buf + (tid + j * 256) * 4);
        }
    };

    // isolate stage ops in the vmcnt counter (afrag/counts loads drained)
    asm volatile("s_waitcnt vmcnt(0)" ::: "memory");
    stage(0);
    stage(1);
    asm volatile("s_waitcnt vmcnt(4)" ::: "memory");   // stage(0) landed
    __builtin_amdgcn_s_barrier();

    for (int k = 0; k < nchunks; ++k) {
        if (k + 2 < nchunks) stage(k + 2);       // depth-2: issue over compute

        const char* base = (const char*)&ldsI[k % 3][0] + (size_t)lane * 16;
#pragma unroll
        for (int rt = 0; rt < 4; ++rt) {
            float4 e0 = *(const float4*)(base + (rt * 2 + 0) * 2048);
            float4 e1 = *(const float4*)(base + (rt * 2 + 0) * 2048 + 1024);
            float4 e2 = *(const float4*)(base + (rt * 2 + 1) * 2048);
            float4 e3 = *(const float4*)(base + (rt * 2 + 1) * 2048 + 1024);
            bf16x8 b0 = cvt8(e0, e1);
            bf16x8 b1 = cvt8(e2, e3);
#pragma unroll
            for (int tt = 0; tt < 4; ++tt) {
                f32x4 acc = {0.f, 0.f, 0.f, 0.f};
                acc = __builtin_amdgcn_mfma_f32_16x16x32_bf16(afrag[tt][0], b0, acc, 0, 0, 0);
                acc = __builtin_amdgcn_mfma_f32_16x16x32_bf16(afrag[tt][1], b1, acc, 0, 0, 0);
#pragma unroll
                for (int i = 0; i < 4; ++i) mx[tt][i] = fmaxf(mx[tt][i], acc[i]);
            }
        }

        if (k + 1 < nchunks) {
            // need stage(k+1) landed; stage(k+2) (4 ops, issued above) may fly on
            if (k + 2 < nchunks)
                asm volatile("s_waitcnt vmcnt(4) lgkmcnt(0)" ::: "memory");
            else
                asm volatile("s_waitcnt vmcnt(0) lgkmcnt(0)" ::: "memory");
            __builtin_amdgcn_s_barrier();
        }
    }

    // ---- cross-lane max over 16 region-cols ----
#pragma unroll
    for (int m = 1; m < 16; m <<= 1) {
#pragma unroll
        for (int tt = 0; tt < 4; ++tt)
#pragma unroll
            for (int i = 0; i < 4; ++i)
                mx[tt][i] = fmaxf(mx[tt][i], __shfl_xor(mx[tt][i], m));
    }

    // ---- masked token sum (C layout: row = q*4 + i) ----
    float bsum = 0.f;
    if (c == 0) {
#pragma unroll
        for (int tt = 0; tt < 4; ++tt)
#pragma unroll
            for (int i = 0; i < 4; ++i) {
                int row = wt0 + tt * 16 + q * 4 + i;
                if (row < ntok) bsum += mx[tt][i];
            }
    }
    for (int off = 32; off; off >>= 1) bsum += __shfl_down(bsum, off);
    if (lane == 0) red[w] = bsum;
    __syncthreads();
    if (tid == 0)
        partials[blk] = (red[0] + red[1] + red[2] + red[3]) / (float)ntok;
}

// 1 block x 384 threads: fold 1536 partials -> 384 sims -> hinge -> loss
__global__ void loss_kernel(const float* __restrict__ partials,
                            float* __restrict__ out) {
    int tid = threadIdx.x;  // 0..383
    __shared__ float simsL[384];
    __shared__ float w6[6];
    const float4* p4 = (const float4*)partials;
    float4 v = p4[tid];
    simsL[tid] = v.x + v.y + v.z + v.w;
    __syncthreads();
    float per = 0.f;
    if (tid < B) {
        float anc  = simsL[tid];
        float simp = simsL[B + tid];
        float iimp = simsL[2 * B + tid];
        per = fmaxf(1.f + iimp - anc, 0.f) + fmaxf(1.f + simp - anc, 0.f);
    }
    for (int off = 32; off; off >>= 1) per += __shfl_down(per, off);
    if ((tid & 63) == 0) w6[tid >> 6] = per;
    __syncthreads();
    if (tid == 0)
        out[0] = (w6[0] + w6[1] + w6[2] + w6[3] + w6[4] + w6[5]) / (float)B;
}

extern "C" void kernel_launch(void* const* d_in, const int* in_sizes, int n_in,
                              void* d_out, int out_size, void* d_ws, size_t ws_size,
                              hipStream_t stream) {
    const float* T     = (const float*)d_in[0];
    const float* I     = (const float*)d_in[1];
    const float* tmask = (const float*)d_in[2];
    const float* imask = (const float*)d_in[3];
    const int*   Iimp  = (const int*)d_in[4];
    const int*   Simp  = (const int*)d_in[5];
    int*   counts   = (int*)d_ws;                 // 256 ints
    float* partials = (float*)d_ws + 256;         // 1536 floats

    count_kernel<<<B, 256, 0, stream>>>(tmask, imask, counts);
    sim_kernel<<<3 * B * 4, 256, 0, stream>>>(T, I, counts, Iimp, Simp, partials);
    loss_kernel<<<1, 384, 0, stream>>>(partials, (float*)d_out);
}

// Round 5
// 122.062 us; speedup vs baseline: 1.4407x; 1.0640x over previous
//
#include <hip/hip_runtime.h>
#include <hip/hip_bf16.h>

#define B 128
#define N 1024
#define L 512
#define D 64

typedef float f32x4 __attribute__((ext_vector_type(4)));
typedef short bf16x8 __attribute__((ext_vector_type(8)));

// 8 fp32 -> 8 bf16 (RNE) via packed HW cvt
__device__ inline bf16x8 cvt8(float4 f0, float4 f1) {
    union { __hip_bfloat162 h2[4]; bf16x8 v; } u;
    u.h2[0] = __float22bfloat162_rn(make_float2(f0.x, f0.y));
    u.h2[1] = __float22bfloat162_rn(make_float2(f0.z, f0.w));
    u.h2[2] = __float22bfloat162_rn(make_float2(f1.x, f1.y));
    u.h2[3] = __float22bfloat162_rn(make_float2(f1.z, f1.w));
    return u.v;
}

// async global->LDS DMA, 16B per lane; LDS dest must be linear base+lane*16
__device__ __forceinline__ void gload16(const void* g, void* l) {
    __builtin_amdgcn_global_load_lds(
        (const __attribute__((address_space(1))) void*)g,
        (__attribute__((address_space(3))) void*)l, 16, 0, 0);
}

// ============================ bf16-workspace path ============================
// Fused pre-pass (one dispatch):
//  blocks [0,B):      ntok[b]/nreg[b] mask counts -> counts[0..2B)
//  blocks [B,B+512):  convert I (fp32, 16MB) -> Ibf (bf16 RNE, 8MB), linear
__global__ __launch_bounds__(256) void prep_kernel(
        const float* __restrict__ tmask, const float* __restrict__ imask,
        const float* __restrict__ I,
        int* __restrict__ counts, unsigned short* __restrict__ Ibf) {
    int blk = blockIdx.x, tid = threadIdx.x;
    if (blk < B) {
        int b = blk;
        int w = tid >> 6, lane = tid & 63;
        float ts = 0.f, is = 0.f;
        const float* tm = tmask + (size_t)b * N;
#pragma unroll
        for (int i = 0; i < N / 256; ++i) ts += tm[tid + i * 256];
        const float* im = imask + (size_t)b * L;
#pragma unroll
        for (int i = 0; i < L / 256; ++i) is += im[tid + i * 256];
        for (int off = 32; off; off >>= 1) {
            ts += __shfl_down(ts, off);
            is += __shfl_down(is, off);
        }
        __shared__ float red[8];
        if (lane == 0) { red[w] = ts; red[4 + w] = is; }
        __syncthreads();
        if (tid == 0) counts[b]     = (int)(red[0] + red[1] + red[2] + red[3] + 0.5f);
        if (tid == 1) counts[B + b] = (int)(red[4] + red[5] + red[6] + red[7] + 0.5f);
    } else {
        // 512 blocks x 256 thr x 4 chunks of 8 elems = 4,194,304 elems exactly
        int t = (blk - B) * 256 + tid;                 // 0..131071
#pragma unroll
        for (int j = 0; j < 4; ++j) {
            size_t ci = (size_t)t + (size_t)j * 131072;
            const float4* p = (const float4*)(I + ci * 8);
            *(bf16x8*)(Ibf + ci * 8) = cvt8(p[0], p[1]);
        }
    }
}

// grid = 1536 blocks (s,b,token-chunk) x 256 thr.
// vs round-3 (fp32-staged, 49.7KB LDS, 3 blocks/CU, 16% occ):
//  - I pre-converted to bf16 -> LDS 3 x 8KB = 24.6KB -> 6 blocks/CU (full
//    1536-block grid co-resident), round-0 conflict-free ds_read_b128
//    fragment layout, ZERO cvt in the hot loop
//  - counted-vmcnt 3-buffer depth-2 pipeline kept (refcheck-proven r3):
//    steady wait = vmcnt(2) [stage(k+1) landed, stage(k+2) in flight];
//    lgkmcnt(0)+s_barrier protects buf[(k+2)%3] rotation vs iter k-1 readers
// LDS bf16 fragment layout, 16B chunk ci in [0,512): g=ci>>6 (=rt*2+h),
//   ln=ci&63: region (g>>1)*16+(ln&15), elems (g&1)*32+(ln>>4)*8 .. +8
__global__ __launch_bounds__(256, 4) void sim_kernel_bf16(
        const float* __restrict__ T, const unsigned short* __restrict__ Ibf,
        const int* __restrict__ counts,
        const int* __restrict__ Iimp, const int* __restrict__ Simp,
        float* __restrict__ partials) {
    int blk = blockIdx.x;          // 0..1535
    int chunk = blk & 3;
    int bs = blk >> 2;
    int b = bs & (B - 1);
    int s = bs >> 7;
    int Tb = b, Ib = b;
    if (s == 1) Tb = Simp[b];
    else if (s == 2) Ib = Iimp[b];

    int tid = threadIdx.x;
    int w = tid >> 6;
    int lane = tid & 63;
    int q = lane >> 4;
    int c = lane & 15;

    int ntok = counts[Tb];         // block-uniform
    int nreg = counts[B + Ib];

    int tok0 = chunk << 8;
    if (chunk != 0 && tok0 >= ntok) {      // ntok >= 256: chunk 0 never exits
        if (tid == 0) partials[blk] = 0.f;
        return;
    }

    __shared__ unsigned short ldsI[3][4096];     // 3 x 8 KB bf16 chunk buffers
    __shared__ float red[4];

    // ---- A fragments: 4 token tiles x 2 K-halves (rows >= ntok masked at sum) ----
    int wt0 = tok0 + w * 64;
    bf16x8 afrag[4][2];
#pragma unroll
    for (int tt = 0; tt < 4; ++tt) {
        const float* trow = T + ((size_t)Tb * N + wt0 + tt * 16 + c) * D;
#pragma unroll
        for (int h = 0; h < 2; ++h) {
            const float4* p = (const float4*)(trow + h * 32 + q * 8);
            afrag[tt][h] = cvt8(p[0], p[1]);
        }
    }

    float mx[4][4];
#pragma unroll
    for (int tt = 0; tt < 4; ++tt)
#pragma unroll
        for (int i = 0; i < 4; ++i) mx[tt][i] = -3.0e38f;

    // ---- staging decode: 2 x 16B DMA per thread per chunk ----
    int rloc[2], eoff[2];
#pragma unroll
    for (int j = 0; j < 2; ++j) {
        int ci = tid + j * 256;
        int g = ci >> 6, ln = ci & 63;
        rloc[j] = (g >> 1) * 16 + (ln & 15);
        eoff[j] = (g & 1) * 32 + (ln >> 4) * 8;
    }
    const unsigned short* Ibase = Ibf + (size_t)Ib * L * D;
    int nchunks = (nreg + 63) >> 6;              // always >= 2 (nreg >= 128)
    int nregm1 = nreg - 1;

    auto stage = [&](int k) {
        unsigned short* buf = &ldsI[k % 3][0];
        int rbase = k << 6;
#pragma unroll
        for (int j = 0; j < 2; ++j) {
            int r = rbase + rloc[j];
            if (r > nregm1) r = nregm1;          // duplicate valid row: max-neutral
            gload16(Ibase + (size_t)r * D + eoff[j], buf + (size_t)(tid + j * 256) * 8);
        }
    };

    // isolate stage ops in the vmcnt counter (afrag/counts loads all consumed)
    asm volatile("s_waitcnt vmcnt(0)" ::: "memory");
    stage(0);
    stage(1);
    asm volatile("s_waitcnt vmcnt(2)" ::: "memory");   // stage(0) landed
    __builtin_amdgcn_s_barrier();

    for (int k = 0; k < nchunks; ++k) {
        if (k + 2 < nchunks) stage(k + 2);       // depth-2: issue over compute

        // full 64-region chunk: 8 ds_read_b128 (conflict-free) + 32 MFMA
        const char* base = (const char*)&ldsI[k % 3][0] + (size_t)lane * 16;
#pragma unroll
        for (int rt = 0; rt < 4; ++rt) {
            bf16x8 b0 = *(const bf16x8*)(base + (rt * 2 + 0) * 1024);
            bf16x8 b1 = *(const bf16x8*)(base + (rt * 2 + 1) * 1024);
#pragma unroll
            for (int tt = 0; tt < 4; ++tt) {
                f32x4 acc = {0.f, 0.f, 0.f, 0.f};
                acc = __builtin_amdgcn_mfma_f32_16x16x32_bf16(afrag[tt][0], b0, acc, 0, 0, 0);
                acc = __builtin_amdgcn_mfma_f32_16x16x32_bf16(afrag[tt][1], b1, acc, 0, 0, 0);
#pragma unroll
                for (int i = 0; i < 4; ++i) mx[tt][i] = fmaxf(mx[tt][i], acc[i]);
            }
        }

        if (k + 1 < nchunks) {
            if (k + 2 < nchunks)
                asm volatile("s_waitcnt vmcnt(2) lgkmcnt(0)" ::: "memory");
            else
                asm volatile("s_waitcnt vmcnt(0) lgkmcnt(0)" ::: "memory");
            __builtin_amdgcn_s_barrier();
        }
    }

    // ---- cross-lane max over 16 region-cols ----
#pragma unroll
    for (int m = 1; m < 16; m <<= 1) {
#pragma unroll
        for (int tt = 0; tt < 4; ++tt)
#pragma unroll
            for (int i = 0; i < 4; ++i)
                mx[tt][i] = fmaxf(mx[tt][i], __shfl_xor(mx[tt][i], m));
    }

    // ---- masked token sum (C layout: row = q*4 + i) ----
    float bsum = 0.f;
    if (c == 0) {
#pragma unroll
        for (int tt = 0; tt < 4; ++tt)
#pragma unroll
            for (int i = 0; i < 4; ++i) {
                int row = wt0 + tt * 16 + q * 4 + i;
                if (row < ntok) bsum += mx[tt][i];
            }
    }
    for (int off = 32; off; off >>= 1) bsum += __shfl_down(bsum, off);
    if (lane == 0) red[w] = bsum;
    __syncthreads();
    if (tid == 0)
        partials[blk] = (red[0] + red[1] + red[2] + red[3]) / (float)ntok;
}

// ===================== fallback path (tiny workspace, r3) =====================
__global__ __launch_bounds__(256) void count_kernel(
        const float* __restrict__ tmask, const float* __restrict__ imask,
        int* __restrict__ counts) {
    int b = blockIdx.x, tid = threadIdx.x;
    int w = tid >> 6, lane = tid & 63;
    float ts = 0.f, is = 0.f;
    const float* tm = tmask + (size_t)b * N;
#pragma unroll
    for (int i = 0; i < N / 256; ++i) ts += tm[tid + i * 256];
    const float* im = imask + (size_t)b * L;
#pragma unroll
    for (int i = 0; i < L / 256; ++i) is += im[tid + i * 256];
    for (int off = 32; off; off >>= 1) {
        ts += __shfl_down(ts, off);
        is += __shfl_down(is, off);
    }
    __shared__ float red[8];
    if (lane == 0) { red[w] = ts; red[4 + w] = is; }
    __syncthreads();
    if (tid == 0) counts[b]     = (int)(red[0] + red[1] + red[2] + red[3] + 0.5f);
    if (tid == 1) counts[B + b] = (int)(red[4] + red[5] + red[6] + red[7] + 0.5f);
}

// verbatim round-3 sim kernel (passed, 53.5us): fp32 DMA staging, 3x16KB LDS
__global__ __launch_bounds__(256, 3) void sim_kernel_f32(
        const float* __restrict__ T, const float* __restrict__ I,
        const int* __restrict__ counts,
        const int* __restrict__ Iimp, const int* __restrict__ Simp,
        float* __restrict__ partials) {
    int blk = blockIdx.x;
    int chunk = blk & 3;
    int bs = blk >> 2;
    int b = bs & (B - 1);
    int s = bs >> 7;
    int Tb = b, Ib = b;
    if (s == 1) Tb = Simp[b];
    else if (s == 2) Ib = Iimp[b];

    int tid = threadIdx.x;
    int w = tid >> 6;
    int lane = tid & 63;
    int q = lane >> 4;
    int c = lane & 15;

    int ntok = counts[Tb];
    int nreg = counts[B + Ib];

    int tok0 = chunk << 8;
    if (chunk != 0 && tok0 >= ntok) {
        if (tid == 0) partials[blk] = 0.f;
        return;
    }

    __shared__ float ldsI[3][4096];
    __shared__ float red[4];

    int wt0 = tok0 + w * 64;
    bf16x8 afrag[4][2];
#pragma unroll
    for (int tt = 0; tt < 4; ++tt) {
        const float* trow = T + ((size_t)Tb * N + wt0 + tt * 16 + c) * D;
#pragma unroll
        for (int h = 0; h < 2; ++h) {
            const float4* p = (const float4*)(trow + h * 32 + q * 8);
            afrag[tt][h] = cvt8(p[0], p[1]);
        }
    }

    float mx[4][4];
#pragma unroll
    for (int tt = 0; tt < 4; ++tt)
#pragma unroll
        for (int i = 0; i < 4; ++i) mx[tt][i] = -3.0e38f;

    int rloc[4], foff[4];
#pragma unroll
    for (int j = 0; j < 4; ++j) {
        int ci = tid + j * 256;
        int fh = ci >> 7, idx = ci & 127, half = idx >> 6, ln2 = idx & 63;
        rloc[j] = (fh >> 1) * 16 + (ln2 & 15);
        foff[j] = (fh & 1) * 32 + (ln2 >> 4) * 8 + half * 4;
    }
    const float* Ibase = I + (size_t)Ib * L * D;
    int nchunks = (nreg + 63) >> 6;
    int nregm1 = nreg - 1;

    auto stage = [&](int k) {
        float* buf = &ldsI[k % 3][0];
        int rbase = k << 6;
#pragma unroll
        for (int j = 0; j < 4; ++j) {
            int r = rbase + rloc[j];
            if (r > nregm1) r = nregm1;
            gload16(Ibase + (size_t)r * D + foff[j], buf + (tid + j * 256) * 4);
        }
    };

    asm volatile("s_waitcnt vmcnt(0)" ::: "memory");
    stage(0);
    stage(1);
    asm volatile("s_waitcnt vmcnt(4)" ::: "memory");
    __builtin_amdgcn_s_barrier();

    for (int k = 0; k < nchunks; ++k) {
        if (k + 2 < nchunks) stage(k + 2);

        const char* base = (const char*)&ldsI[k % 3][0] + (size_t)lane * 16;
#pragma unroll
        for (int rt = 0; rt < 4; ++rt) {
            float4 e0 = *(const float4*)(base + (rt * 2 + 0) * 2048);
            float4 e1 = *(const float4*)(base + (rt * 2 + 0) * 2048 + 1024);
            float4 e2 = *(const float4*)(base + (rt * 2 + 1) * 2048);
            float4 e3 = *(const float4*)(base + (rt * 2 + 1) * 2048 + 1024);
            bf16x8 b0 = cvt8(e0, e1);
            bf16x8 b1 = cvt8(e2, e3);
#pragma unroll
            for (int tt = 0; tt < 4; ++tt) {
                f32x4 acc = {0.f, 0.f, 0.f, 0.f};
                acc = __builtin_amdgcn_mfma_f32_16x16x32_bf16(afrag[tt][0], b0, acc, 0, 0, 0);
                acc = __builtin_amdgcn_mfma_f32_16x16x32_bf16(afrag[tt][1], b1, acc, 0, 0, 0);
#pragma unroll
                for (int i = 0; i < 4; ++i) mx[tt][i] = fmaxf(mx[tt][i], acc[i]);
            }
        }

        if (k + 1 < nchunks) {
            if (k + 2 < nchunks)
                asm volatile("s_waitcnt vmcnt(4) lgkmcnt(0)" ::: "memory");
            else
                asm volatile("s_waitcnt vmcnt(0) lgkmcnt(0)" ::: "memory");
            __builtin_amdgcn_s_barrier();
        }
    }

#pragma unroll
    for (int m = 1; m < 16; m <<= 1) {
#pragma unroll
        for (int tt = 0; tt < 4; ++tt)
#pragma unroll
            for (int i = 0; i < 4; ++i)
                mx[tt][i] = fmaxf(mx[tt][i], __shfl_xor(mx[tt][i], m));
    }

    float bsum = 0.f;
    if (c == 0) {
#pragma unroll
        for (int tt = 0; tt < 4; ++tt)
#pragma unroll
            for (int i = 0; i < 4; ++i) {
                int row = wt0 + tt * 16 + q * 4 + i;
                if (row < ntok) bsum += mx[tt][i];
            }
    }
    for (int off = 32; off; off >>= 1) bsum += __shfl_down(bsum, off);
    if (lane == 0) red[w] = bsum;
    __syncthreads();
    if (tid == 0)
        partials[blk] = (red[0] + red[1] + red[2] + red[3]) / (float)ntok;
}

// 1 block x 384 threads: fold 1536 partials -> 384 sims -> hinge -> loss
__global__ void loss_kernel(const float* __restrict__ partials,
                            float* __restrict__ out) {
    int tid = threadIdx.x;  // 0..383
    __shared__ float simsL[384];
    __shared__ float w6[6];
    const float4* p4 = (const float4*)partials;
    float4 v = p4[tid];
    simsL[tid] = v.x + v.y + v.z + v.w;
    __syncthreads();
    float per = 0.f;
    if (tid < B) {
        float anc  = simsL[tid];
        float simp = simsL[B + tid];
        float iimp = simsL[2 * B + tid];
        per = fmaxf(1.f + iimp - anc, 0.f) + fmaxf(1.f + simp - anc, 0.f);
    }
    for (int off = 32; off; off >>= 1) per += __shfl_down(per, off);
    if ((tid & 63) == 0) w6[tid >> 6] = per;
    __syncthreads();
    if (tid == 0)
        out[0] = (w6[0] + w6[1] + w6[2] + w6[3] + w6[4] + w6[5]) / (float)B;
}

extern "C" void kernel_launch(void* const* d_in, const int* in_sizes, int n_in,
                              void* d_out, int out_size, void* d_ws, size_t ws_size,
                              hipStream_t stream) {
    const float* T     = (const float*)d_in[0];
    const float* I     = (const float*)d_in[1];
    const float* tmask = (const float*)d_in[2];
    const float* imask = (const float*)d_in[3];
    const int*   Iimp  = (const int*)d_in[4];
    const int*   Simp  = (const int*)d_in[5];
    // ws layout: counts[256] ints | partials[1536] floats | (opt) Ibf bf16
    int*   counts   = (int*)d_ws;
    float* partials = (float*)((char*)d_ws + 1024);
    size_t need_bf16 = 7168 + (size_t)B * L * D * sizeof(unsigned short);

    if (ws_size >= need_bf16) {
        unsigned short* Ibf = (unsigned short*)((char*)d_ws + 7168);
        prep_kernel<<<B + 512, 256, 0, stream>>>(tmask, imask, I, counts, Ibf);
        sim_kernel_bf16<<<3 * B * 4, 256, 0, stream>>>(T, Ibf, counts, Iimp, Simp, partials);
    } else {
        count_kernel<<<B, 256, 0, stream>>>(tmask, imask, counts);
        sim_kernel_f32<<<3 * B * 4, 256, 0, stream>>>(T, I, counts, Iimp, Simp, partials);
    }
    loss_kernel<<<1, 384, 0, stream>>>(partials, (float*)d_out);
}